// Round 3
// baseline (460.529 us; speedup 1.0000x reference)
//
#include <hip/hip_runtime.h>
#include <hip/hip_bf16.h>

typedef __attribute__((ext_vector_type(8))) short short8;
typedef __attribute__((ext_vector_type(4))) short short4b;
typedef __attribute__((ext_vector_type(4))) int int4v;
typedef __attribute__((ext_vector_type(4))) float f32x4;

#define MFMA_BF16(A_, B_, C_) __builtin_amdgcn_mfma_f32_16x16x32_bf16((A_), (B_), (C_), 0, 0, 0)

// 16x16x16 bf16 MFMA: device pass resolves the real builtin (verified present on
// gfx950 — R2's device pass compiled it); host pass only needs to PARSE device
// bodies, so give it a type-correct stub. (__has_builtin is false for aux-target
// builtins in the HIP host pass — that's what broke R2.)
#if defined(__HIP_DEVICE_COMPILE__)
#if __has_builtin(__builtin_amdgcn_mfma_f32_16x16x16bf16_1k)
#define MFMA16(A_, B_, C_) __builtin_amdgcn_mfma_f32_16x16x16bf16_1k((A_), (B_), (C_), 0, 0, 0)
#else
#define MFMA16(A_, B_, C_) __builtin_amdgcn_mfma_f32_16x16x16_bf16((A_), (B_), (C_), 0, 0, 0)
#endif
#else
#define MFMA16(A_, B_, C_) (C_)
#endif

__device__ __forceinline__ unsigned short f2bf(float f) {
  unsigned int u = __builtin_bit_cast(unsigned int, f);
  return (unsigned short)((u + 0x7FFFu + ((u >> 16) & 1u)) >> 16);
}

__device__ __forceinline__ void gll16(const unsigned short* g, unsigned short* l) {
  __builtin_amdgcn_global_load_lds((const __attribute__((address_space(1))) void*)g,
                                   (__attribute__((address_space(3))) void*)l, 16, 0, 0);
}

// ---------------------------------------------------------------- convert
#define NX (8192 * 1024)
#define NW (1024 * 1024)

__global__ void convert_k(const float* __restrict__ x,
                          const float* __restrict__ wq, const float* __restrict__ wk,
                          const float* __restrict__ wv, const float* __restrict__ wo,
                          unsigned short* __restrict__ xb,
                          unsigned short* __restrict__ wqkv,
                          unsigned short* __restrict__ wob) {
  size_t i = ((size_t)blockIdx.x * blockDim.x + threadIdx.x) * 4;
  const float* sp;
  unsigned short* dp;
  if (i < (size_t)NX) {
    sp = x + i; dp = xb + i;
  } else {
    size_t j = i - NX;
    if (j < (size_t)NW)               { sp = wq + j;            dp = wqkv + j; }
    else if (j < (size_t)(2 * NW))    { sp = wk + (j - NW);     dp = wqkv + j; }
    else if (j < (size_t)(3 * NW))    { sp = wv + (j - 2 * NW); dp = wqkv + j; }
    else                              { sp = wo + (j - 3 * NW); dp = wob + (j - 3 * NW); }
  }
  float4 v = *(const float4*)sp;
  ushort4 o;
  o.x = f2bf(v.x); o.y = f2bf(v.y); o.z = f2bf(v.z); o.w = f2bf(v.w);
  *(ushort4*)dp = o;
}

// ---------------------------------------------------------------- GEMM1: QKV projection
// A = x_bf16 [8192][1024], Bw = [Wq;Wk;Wv] bf16 [3072][1024] (B^T layout)
// writes Q (pre-scaled by 1/8), K -> [bh][s][64], V -> transposed [bh][64][s]
__global__ __launch_bounds__(256, 2) void gemm_qkv_k(
    const unsigned short* __restrict__ A, const unsigned short* __restrict__ Bw,
    const float* __restrict__ bq, const float* __restrict__ bk, const float* __restrict__ bv,
    unsigned short* __restrict__ qb, unsigned short* __restrict__ kb,
    unsigned short* __restrict__ vtb) {
  const int K = 1024;
  __shared__ __align__(16) unsigned short lA[128 * 32];
  __shared__ __align__(16) unsigned short lB[128 * 32];
  const int tid = threadIdx.x;
  const int lane = tid & 63;
  const int w = tid >> 6;
  const int wm = w >> 1, wn = w & 1;
  const int m0 = blockIdx.x * 128, n0 = blockIdx.y * 128;
  const int l15 = lane & 15, lg = lane >> 4;

  const f32x4 zf = {0.0f, 0.0f, 0.0f, 0.0f};
  f32x4 acc[4][4];
#pragma unroll
  for (int mi = 0; mi < 4; ++mi)
#pragma unroll
    for (int ni = 0; ni < 4; ++ni) acc[mi][ni] = zf;

  const int c0 = tid, c1 = tid + 256;
  const int r0 = c0 >> 2, k0c = (c0 & 3) * 8;
  const int r1 = c1 >> 2, k1c = (c1 & 3) * 8;
  const unsigned short* ga0 = A + (size_t)(m0 + r0) * K + k0c;
  const unsigned short* ga1 = A + (size_t)(m0 + r1) * K + k1c;
  const unsigned short* gb0 = Bw + (size_t)(n0 + r0) * K + k0c;
  const unsigned short* gb1 = Bw + (size_t)(n0 + r1) * K + k1c;

  for (int kt = 0; kt < K; kt += 32) {
    __syncthreads();
    gll16(ga0 + kt, lA + c0 * 8);
    gll16(ga1 + kt, lA + c1 * 8);
    gll16(gb0 + kt, lB + c0 * 8);
    gll16(gb1 + kt, lB + c1 * 8);
    __syncthreads();
    short8 af[4], bf[4];
#pragma unroll
    for (int mi = 0; mi < 4; ++mi)
      af[mi] = *(const short8*)&lA[(wm * 64 + mi * 16 + l15) * 32 + lg * 8];
#pragma unroll
    for (int ni = 0; ni < 4; ++ni)
      bf[ni] = *(const short8*)&lB[(wn * 64 + ni * 16 + l15) * 32 + lg * 8];
#pragma unroll
    for (int mi = 0; mi < 4; ++mi)
#pragma unroll
      for (int ni = 0; ni < 4; ++ni)
        acc[mi][ni] = MFMA_BF16(af[mi], bf[ni], acc[mi][ni]);
  }

  const int which = n0 >> 10;  // 0:Q 1:K 2:V  (n0 multiple of 128)
  const float* bias = (which == 0) ? bq : (which == 1) ? bk : bv;
  const float qs = (which == 0) ? 0.125f : 1.0f;  // fold softmax 1/sqrt(64) into Q
#pragma unroll
  for (int ni = 0; ni < 4; ++ni) {
    const int n = n0 + wn * 64 + ni * 16 + l15;
    const int nn = n & 1023;
    const float bia = bias[nn];
    const int h = nn >> 6, hd = nn & 63;
#pragma unroll
    for (int mi = 0; mi < 4; ++mi) {
      const int mb = m0 + wm * 64 + mi * 16 + lg * 4;
      const int b = mb >> 11, s = mb & 2047;
      const int bh = b * 16 + h;
      if (which < 2) {
        unsigned short* dst = ((which == 0) ? qb : kb) + ((size_t)bh * 2048 + s) * 64 + hd;
#pragma unroll
        for (int r = 0; r < 4; ++r)
          dst[(size_t)r * 64] = f2bf((acc[mi][ni][r] + bia) * qs);
      } else {
        ushort4 pk;
        pk.x = f2bf(acc[mi][ni][0] + bia);
        pk.y = f2bf(acc[mi][ni][1] + bia);
        pk.z = f2bf(acc[mi][ni][2] + bia);
        pk.w = f2bf(acc[mi][ni][3] + bia);
        *(ushort4*)(vtb + ((size_t)bh * 64 + hd) * 2048 + s) = pk;
      }
    }
  }
}

// ---------------------------------------------------------------- flash attention v2
// Swapped QK^T (S^T = K·Q^T), softmax fully in-register, PV via 16x16x16 MFMA.
// 1 wave per block, 32 q-rows per wave, no LDS, no barriers.
// Q,K: [bh][2048][64] bf16 (Q pre-scaled by 1/8); VT: [bh][64][2048] bf16.
__global__ __launch_bounds__(64, 3) void attn_k(
    const unsigned short* __restrict__ Qb, const unsigned short* __restrict__ Kb,
    const unsigned short* __restrict__ VTb, const int* __restrict__ mask,
    unsigned short* __restrict__ vals) {
  const int lane = threadIdx.x & 63;
  const int l15 = lane & 15, lg = lane >> 4;
  const int qt = blockIdx.x, bh = blockIdx.y;
  const int b = bh >> 4, h = bh & 15;
  const int q0 = qt * 32;
  const unsigned short* Qp = Qb + (size_t)bh * (2048 * 64);
  const unsigned short* Kp = Kb + (size_t)bh * (2048 * 64);
  const unsigned short* Vp = VTb + (size_t)bh * (64 * 2048);
  const int* mp = mask + b * 2048;

  // Q as B-operand fragments: B[k=d][col=q] -> lane holds Q[q=l15][d=lg*8+j]
  short8 qf[2][2];
#pragma unroll
  for (int mi = 0; mi < 2; ++mi)
#pragma unroll
    for (int ks = 0; ks < 2; ++ks)
      qf[mi][ks] = *(const short8*)(Qp + (size_t)(q0 + mi * 16 + l15) * 64 + ks * 32 + lg * 8);

  const f32x4 zf = {0.0f, 0.0f, 0.0f, 0.0f};
  f32x4 acc[2][4];  // O^T[d][q]: col=l15=q, row=lg*4+r=d (within hf block)
  float mrun[2], lrun[2];
#pragma unroll
  for (int mi = 0; mi < 2; ++mi) {
#pragma unroll
    for (int hf = 0; hf < 4; ++hf) acc[mi][hf] = zf;
    mrun[mi] = -1e30f; lrun[mi] = 0.0f;
  }

  for (int kv = 0; kv < 2048; kv += 64) {
    short8 kf[4][2];
    short4b vf[4][4];
    int4v mv[4];
#pragma unroll
    for (int f = 0; f < 4; ++f) {
      kf[f][0] = *(const short8*)(Kp + (size_t)(kv + f * 16 + l15) * 64 + lg * 8);
      kf[f][1] = *(const short8*)(Kp + (size_t)(kv + f * 16 + l15) * 64 + 32 + lg * 8);
      mv[f] = *(const int4v*)(mp + kv + f * 16 + lg * 4);
    }
#pragma unroll
    for (int hf = 0; hf < 4; ++hf)
#pragma unroll
      for (int f = 0; f < 4; ++f)
        vf[hf][f] = *(const short4b*)(Vp + (size_t)(hf * 16 + l15) * 2048 + kv + f * 16 + lg * 4);

    // S^T[kv][q]: col=l15=q, row=lg*4+r=kv (within f block)
    f32x4 sc[2][4];
#pragma unroll
    for (int mi = 0; mi < 2; ++mi)
#pragma unroll
      for (int f = 0; f < 4; ++f) {
        f32x4 t = MFMA_BF16(kf[f][0], qf[mi][0], zf);
        sc[mi][f] = MFMA_BF16(kf[f][1], qf[mi][1], t);
      }

#pragma unroll
    for (int mi = 0; mi < 2; ++mi) {
      // row max: 16 local + 2 shuffles (max over raw scores is a valid stabilizer)
      float t = sc[mi][0][0];
#pragma unroll
      for (int f = 0; f < 4; ++f)
#pragma unroll
        for (int r = 0; r < 4; ++r) t = fmaxf(t, sc[mi][f][r]);
      t = fmaxf(t, __shfl_xor(t, 16));
      t = fmaxf(t, __shfl_xor(t, 32));

      // defer-max (T13, THR=8): rescale only when max grew materially
      if (__any(t > mrun[mi] + 8.0f)) {
        float mn = fmaxf(mrun[mi], t);
        float scl = __expf(mrun[mi] - mn);
        mrun[mi] = mn;
        lrun[mi] *= scl;
#pragma unroll
        for (int hf = 0; hf < 4; ++hf)
#pragma unroll
          for (int r = 0; r < 4; ++r) acc[mi][hf][r] *= scl;
      }

      float rs = 0.0f;
      short4b pb[4];  // P^T as B-operand of 16x16x16: B[k=lg*4+r][col=l15]
#pragma unroll
      for (int f = 0; f < 4; ++f) {
#pragma unroll
        for (int r = 0; r < 4; ++r) {
          float p = __expf(sc[mi][f][r] - mrun[mi]);
          p = (mv[f][r] != 0) ? p : 0.0f;  // mask after exp: P=0 for masked kv
          rs += p;
          __hip_bfloat16 hb = __float2bfloat16(p);
          pb[f][r] = (short)__builtin_bit_cast(unsigned short, hb);
        }
      }
      rs += __shfl_xor(rs, 16);
      rs += __shfl_xor(rs, 32);
      lrun[mi] += rs;

      // PV: O^T += V^T · P^T, 16x16x16 (A=V^T fragment, B=P^T fragment)
#pragma unroll
      for (int hf = 0; hf < 4; ++hf)
#pragma unroll
        for (int f = 0; f < 4; ++f)
          acc[mi][hf] = MFMA16(vf[hf][f], pb[f], acc[mi][hf]);
    }
  }

#pragma unroll
  for (int mi = 0; mi < 2; ++mi) {
    float inv = 1.0f / lrun[mi];
    const int q = q0 + mi * 16 + l15;
    unsigned short* dst = vals + ((size_t)b * 2048 + q) * 1024 + h * 64 + lg * 4;
#pragma unroll
    for (int hf = 0; hf < 4; ++hf) {
      ushort4 o;
      o.x = f2bf(acc[mi][hf][0] * inv);
      o.y = f2bf(acc[mi][hf][1] * inv);
      o.z = f2bf(acc[mi][hf][2] * inv);
      o.w = f2bf(acc[mi][hf][3] * inv);
      *(ushort4*)(dst + hf * 16) = o;
    }
  }
}

// ---------------------------------------------------------------- GEMM2: output projection
__global__ __launch_bounds__(256, 2) void gemm_out_k(
    const unsigned short* __restrict__ A, const unsigned short* __restrict__ Bw,
    const float* __restrict__ bo, float* __restrict__ out) {
  const int K = 1024;
  __shared__ __align__(16) unsigned short lA[128 * 32];
  __shared__ __align__(16) unsigned short lB[128 * 32];
  const int tid = threadIdx.x;
  const int lane = tid & 63;
  const int w = tid >> 6;
  const int wm = w >> 1, wn = w & 1;
  const int m0 = blockIdx.x * 128, n0 = blockIdx.y * 128;
  const int l15 = lane & 15, lg = lane >> 4;

  const f32x4 zf = {0.0f, 0.0f, 0.0f, 0.0f};
  f32x4 acc[4][4];
#pragma unroll
  for (int mi = 0; mi < 4; ++mi)
#pragma unroll
    for (int ni = 0; ni < 4; ++ni) acc[mi][ni] = zf;

  const int c0 = tid, c1 = tid + 256;
  const int r0 = c0 >> 2, k0c = (c0 & 3) * 8;
  const int r1 = c1 >> 2, k1c = (c1 & 3) * 8;
  const unsigned short* ga0 = A + (size_t)(m0 + r0) * K + k0c;
  const unsigned short* ga1 = A + (size_t)(m0 + r1) * K + k1c;
  const unsigned short* gb0 = Bw + (size_t)(n0 + r0) * K + k0c;
  const unsigned short* gb1 = Bw + (size_t)(n0 + r1) * K + k1c;

  for (int kt = 0; kt < K; kt += 32) {
    __syncthreads();
    gll16(ga0 + kt, lA + c0 * 8);
    gll16(ga1 + kt, lA + c1 * 8);
    gll16(gb0 + kt, lB + c0 * 8);
    gll16(gb1 + kt, lB + c1 * 8);
    __syncthreads();
    short8 af[4], bf[4];
#pragma unroll
    for (int mi = 0; mi < 4; ++mi)
      af[mi] = *(const short8*)&lA[(wm * 64 + mi * 16 + l15) * 32 + lg * 8];
#pragma unroll
    for (int ni = 0; ni < 4; ++ni)
      bf[ni] = *(const short8*)&lB[(wn * 64 + ni * 16 + l15) * 32 + lg * 8];
#pragma unroll
    for (int mi = 0; mi < 4; ++mi)
#pragma unroll
      for (int ni = 0; ni < 4; ++ni)
        acc[mi][ni] = MFMA_BF16(af[mi], bf[ni], acc[mi][ni]);
  }

#pragma unroll
  for (int ni = 0; ni < 4; ++ni) {
    const int n = n0 + wn * 64 + ni * 16 + l15;
    const float bia = bo[n];
#pragma unroll
    for (int mi = 0; mi < 4; ++mi) {
      const int mb = m0 + wm * 64 + mi * 16 + lg * 4;
#pragma unroll
      for (int r = 0; r < 4; ++r)
        out[(size_t)(mb + r) * 1024 + n] = acc[mi][ni][r] + bia;
    }
  }
}

// ---------------------------------------------------------------- launch
extern "C" void kernel_launch(void* const* d_in, const int* in_sizes, int n_in,
                              void* d_out, int out_size, void* d_ws, size_t ws_size,
                              hipStream_t stream) {
  const float* x  = (const float*)d_in[0];
  const int* mask = (const int*)d_in[1];
  const float* Wq = (const float*)d_in[2];
  const float* bq = (const float*)d_in[3];
  const float* Wk = (const float*)d_in[4];
  const float* bk = (const float*)d_in[5];
  const float* Wv = (const float*)d_in[6];
  const float* bv = (const float*)d_in[7];
  const float* Wo = (const float*)d_in[8];
  const float* bo = (const float*)d_in[9];
  float* out = (float*)d_out;

  unsigned short* xb   = (unsigned short*)d_ws;            // 8192*1024
  unsigned short* wqkv = xb + (size_t)8192 * 1024;         // 3072*1024
  unsigned short* wob  = wqkv + (size_t)3072 * 1024;       // 1024*1024
  unsigned short* qb   = wob + (size_t)1024 * 1024;        // 64*2048*64
  unsigned short* kb   = qb + (size_t)64 * 2048 * 64;
  unsigned short* vtb  = kb + (size_t)64 * 2048 * 64;
  unsigned short* vals = vtb + (size_t)64 * 2048 * 64;     // 8192*1024

  convert_k<<<dim3(12288), dim3(256), 0, stream>>>(x, Wq, Wk, Wv, Wo, xb, wqkv, wob);
  gemm_qkv_k<<<dim3(64, 24), dim3(256), 0, stream>>>(xb, wqkv, bq, bk, bv, qb, kb, vtb);
  attn_k<<<dim3(64, 64), dim3(64), 0, stream>>>(qb, kb, vtb, mask, vals);
  gemm_out_k<<<dim3(64, 8), dim3(256), 0, stream>>>(vals, wob, bo, out);
}

// Round 4
// 232.488 us; speedup vs baseline: 1.9809x; 1.9809x over previous
//
#include <hip/hip_runtime.h>
#include <hip/hip_bf16.h>

typedef __attribute__((ext_vector_type(8))) short short8;
typedef __attribute__((ext_vector_type(4))) short short4b;
typedef __attribute__((ext_vector_type(4))) int int4v;
typedef __attribute__((ext_vector_type(4))) float f32x4;

#define MFMA_BF16(A_, B_, C_) __builtin_amdgcn_mfma_f32_16x16x32_bf16((A_), (B_), (C_), 0, 0, 0)

// 16x16x16 bf16 MFMA: device pass resolves the real builtin; host pass only
// parses device bodies (aux-target __has_builtin is false on host — R2 lesson).
#if defined(__HIP_DEVICE_COMPILE__)
#if __has_builtin(__builtin_amdgcn_mfma_f32_16x16x16bf16_1k)
#define MFMA16(A_, B_, C_) __builtin_amdgcn_mfma_f32_16x16x16bf16_1k((A_), (B_), (C_), 0, 0, 0)
#else
#define MFMA16(A_, B_, C_) __builtin_amdgcn_mfma_f32_16x16x16_bf16((A_), (B_), (C_), 0, 0, 0)
#endif
#else
#define MFMA16(A_, B_, C_) (C_)
#endif

__device__ __forceinline__ unsigned short f2bf(float f) {
  unsigned int u = __builtin_bit_cast(unsigned int, f);
  return (unsigned short)((u + 0x7FFFu + ((u >> 16) & 1u)) >> 16);
}

__device__ __forceinline__ void gll16(const unsigned short* g, unsigned short* l) {
  __builtin_amdgcn_global_load_lds((const __attribute__((address_space(1))) void*)g,
                                   (__attribute__((address_space(3))) void*)l, 16, 0, 0);
}

// ---------------------------------------------------------------- convert
#define NX (8192 * 1024)
#define NW (1024 * 1024)

__global__ void convert_k(const float* __restrict__ x,
                          const float* __restrict__ wq, const float* __restrict__ wk,
                          const float* __restrict__ wv, const float* __restrict__ wo,
                          unsigned short* __restrict__ xb,
                          unsigned short* __restrict__ wqkv,
                          unsigned short* __restrict__ wob) {
  size_t i = ((size_t)blockIdx.x * blockDim.x + threadIdx.x) * 4;
  const float* sp;
  unsigned short* dp;
  if (i < (size_t)NX) {
    sp = x + i; dp = xb + i;
  } else {
    size_t j = i - NX;
    if (j < (size_t)NW)               { sp = wq + j;            dp = wqkv + j; }
    else if (j < (size_t)(2 * NW))    { sp = wk + (j - NW);     dp = wqkv + j; }
    else if (j < (size_t)(3 * NW))    { sp = wv + (j - 2 * NW); dp = wqkv + j; }
    else                              { sp = wo + (j - 3 * NW); dp = wob + (j - 3 * NW); }
  }
  float4 v = *(const float4*)sp;
  ushort4 o;
  o.x = f2bf(v.x); o.y = f2bf(v.y); o.z = f2bf(v.z); o.w = f2bf(v.w);
  *(ushort4*)dp = o;
}

// ---------------------------------------------------------------- GEMM1: QKV projection
// A = x_bf16 [8192][1024], Bw = [Wq;Wk;Wv] bf16 [3072][1024] (B^T layout)
// Q (pre-scaled 1/8), K -> [bh][s][64]
// V -> tiled transposed: vtb[bh][s>>6][d(64)][kvp(64)], kvp = permuted kv-in-tile
//      so attention's 16B LDS read yields two MFMA16 A-fragments.
__global__ __launch_bounds__(256, 2) void gemm_qkv_k(
    const unsigned short* __restrict__ A, const unsigned short* __restrict__ Bw,
    const float* __restrict__ bq, const float* __restrict__ bk, const float* __restrict__ bv,
    unsigned short* __restrict__ qb, unsigned short* __restrict__ kb,
    unsigned short* __restrict__ vtb) {
  const int K = 1024;
  __shared__ __align__(16) unsigned short lA[128 * 32];
  __shared__ __align__(16) unsigned short lB[128 * 32];
  const int tid = threadIdx.x;
  const int lane = tid & 63;
  const int w = tid >> 6;
  const int wm = w >> 1, wn = w & 1;
  const int m0 = blockIdx.x * 128, n0 = blockIdx.y * 128;
  const int l15 = lane & 15, lg = lane >> 4;

  const f32x4 zf = {0.0f, 0.0f, 0.0f, 0.0f};
  f32x4 acc[4][4];
#pragma unroll
  for (int mi = 0; mi < 4; ++mi)
#pragma unroll
    for (int ni = 0; ni < 4; ++ni) acc[mi][ni] = zf;

  const int c0 = tid, c1 = tid + 256;
  const int r0 = c0 >> 2, k0c = (c0 & 3) * 8;
  const int r1 = c1 >> 2, k1c = (c1 & 3) * 8;
  const unsigned short* ga0 = A + (size_t)(m0 + r0) * K + k0c;
  const unsigned short* ga1 = A + (size_t)(m0 + r1) * K + k1c;
  const unsigned short* gb0 = Bw + (size_t)(n0 + r0) * K + k0c;
  const unsigned short* gb1 = Bw + (size_t)(n0 + r1) * K + k1c;

  for (int kt = 0; kt < K; kt += 32) {
    __syncthreads();
    gll16(ga0 + kt, lA + c0 * 8);
    gll16(ga1 + kt, lA + c1 * 8);
    gll16(gb0 + kt, lB + c0 * 8);
    gll16(gb1 + kt, lB + c1 * 8);
    __syncthreads();
    short8 af[4], bf[4];
#pragma unroll
    for (int mi = 0; mi < 4; ++mi)
      af[mi] = *(const short8*)&lA[(wm * 64 + mi * 16 + l15) * 32 + lg * 8];
#pragma unroll
    for (int ni = 0; ni < 4; ++ni)
      bf[ni] = *(const short8*)&lB[(wn * 64 + ni * 16 + l15) * 32 + lg * 8];
#pragma unroll
    for (int mi = 0; mi < 4; ++mi)
#pragma unroll
      for (int ni = 0; ni < 4; ++ni)
        acc[mi][ni] = MFMA_BF16(af[mi], bf[ni], acc[mi][ni]);
  }

  const int which = n0 >> 10;  // 0:Q 1:K 2:V
  const float* bias = (which == 0) ? bq : (which == 1) ? bk : bv;
  const float qs = (which == 0) ? 0.125f : 1.0f;
#pragma unroll
  for (int ni = 0; ni < 4; ++ni) {
    const int n = n0 + wn * 64 + ni * 16 + l15;
    const int nn = n & 1023;
    const float bia = bias[nn];
    const int h = nn >> 6, hd = nn & 63;
#pragma unroll
    for (int mi = 0; mi < 4; ++mi) {
      const int mb = m0 + wm * 64 + mi * 16 + lg * 4;
      const int b = mb >> 11, s = mb & 2047;
      const int bh = b * 16 + h;
      if (which < 2) {
        unsigned short* dst = ((which == 0) ? qb : kb) + ((size_t)bh * 2048 + s) * 64 + hd;
#pragma unroll
        for (int r = 0; r < 4; ++r)
          dst[(size_t)r * 64] = f2bf((acc[mi][ni][r] + bia) * qs);
      } else {
        // kv-in-tile = f*16 + lgk*4 + r  ->  kvp = (f>>1)*32 + lgk*8 + (f&1)*4 + r
        const int tle = s >> 6, w64 = s & 63;
        const int f = w64 >> 4, lgk = (w64 >> 2) & 3;
        const int kvp0 = (f >> 1) * 32 + lgk * 8 + (f & 1) * 4;
        ushort4 pk;
        pk.x = f2bf(acc[mi][ni][0] + bia);
        pk.y = f2bf(acc[mi][ni][1] + bia);
        pk.z = f2bf(acc[mi][ni][2] + bia);
        pk.w = f2bf(acc[mi][ni][3] + bia);
        *(ushort4*)(vtb + (((size_t)bh * 32 + tle) * 64 + hd) * 64 + kvp0) = pk;
      }
    }
  }
}

// ---------------------------------------------------------------- flash attention v3
// 4 waves/block (QBLK=128, 32 q-rows/wave), swapped QK^T + in-register softmax
// (validated R3), K/V^T double-buffered in LDS via global_load_lds with
// pre-swizzled source (XOR on 16B columns breaks the 128B-row bank conflict),
// one stage + one barrier per kv-tile (minimum 2-phase), setprio on MFMA.
__global__ __launch_bounds__(256, 2) void attn_k(
    const unsigned short* __restrict__ Qb, const unsigned short* __restrict__ Kb,
    const unsigned short* __restrict__ VTb, const int* __restrict__ mask,
    unsigned short* __restrict__ vals) {
  __shared__ __align__(16) unsigned short Kl[2][64 * 64];
  __shared__ __align__(16) unsigned short Vl[2][64 * 64];
  const int tid = threadIdx.x;
  const int lane = tid & 63;
  const int w = tid >> 6;
  const int l15 = lane & 15, lg = lane >> 4;

  // XCD-grouped swizzle: blocks of one XCD cover 8 whole bh (K/V stay in its L2)
  const int bid = blockIdx.x;                    // 0..1023
  const int wk = (bid & 7) * 128 + (bid >> 3);   // bijective
  const int bh = wk >> 4, qt = wk & 15;
  const int b = bh >> 4, h = bh & 15;
  const int q0 = qt * 128 + w * 32;

  const unsigned short* Qp = Qb + (size_t)bh * (2048 * 64);
  const int* mp = mask + b * 2048;

  // staging addressing: thread t covers rows {t>>3, t>>3+32}, 16B col (t&7),
  // source column XOR-swizzled so the linear LDS dest ends up swizzled.
  const int srow = tid >> 3;
  const int scol = ((tid & 7) ^ (srow & 7)) * 8;   // (srow+32)&7 == srow&7
  const unsigned short* kSrc = Kb + (size_t)bh * (2048 * 64) + srow * 64 + scol;
  const unsigned short* vSrc = VTb + (size_t)bh * (32 * 64 * 64) + srow * 64 + scol;

  short8 qf[2][2];
#pragma unroll
  for (int mi = 0; mi < 2; ++mi)
#pragma unroll
    for (int ks = 0; ks < 2; ++ks)
      qf[mi][ks] = *(const short8*)(Qp + (size_t)(q0 + mi * 16 + l15) * 64 + ks * 32 + lg * 8);

  const f32x4 zf = {0.0f, 0.0f, 0.0f, 0.0f};
  f32x4 acc[2][4];
  float mrun[2], lrun[2];
#pragma unroll
  for (int mi = 0; mi < 2; ++mi) {
#pragma unroll
    for (int hf = 0; hf < 4; ++hf) acc[mi][hf] = zf;
    mrun[mi] = -1e30f; lrun[mi] = 0.0f;
  }

  // prologue: stage tile 0 into buf 0
  gll16(kSrc, &Kl[0][tid * 8]);
  gll16(kSrc + 2048, &Kl[0][tid * 8 + 2048]);
  gll16(vSrc, &Vl[0][tid * 8]);
  gll16(vSrc + 2048, &Vl[0][tid * 8 + 2048]);
  __syncthreads();

  for (int t = 0; t < 32; ++t) {
    const int cur = t & 1;
    if (t < 31) {  // stage next tile into the other buffer
      const size_t off = (size_t)(t + 1) * 4096;
      unsigned short* kd = &Kl[cur ^ 1][tid * 8];
      unsigned short* vd = &Vl[cur ^ 1][tid * 8];
      gll16(kSrc + off, kd);
      gll16(kSrc + off + 2048, kd + 2048);
      gll16(vSrc + off, vd);
      gll16(vSrc + off + 2048, vd + 2048);
    }
    const unsigned short* Kc = Kl[cur];
    const unsigned short* Vc = Vl[cur];
    const int kv0 = t * 64;

    int4v mv[4];
#pragma unroll
    for (int f = 0; f < 4; ++f) mv[f] = *(const int4v*)(mp + kv0 + f * 16 + lg * 4);

    // fragments from swizzled LDS: logical col c stored at c ^ (row&7)
    short8 kf[4][2], vv[4][2];
#pragma unroll
    for (int f = 0; f < 4; ++f)
#pragma unroll
      for (int ks = 0; ks < 2; ++ks)
        kf[f][ks] = *(const short8*)&Kc[(f * 16 + l15) * 64 + (((ks * 4 + lg) ^ (l15 & 7)) * 8)];
#pragma unroll
    for (int hf = 0; hf < 4; ++hf)
#pragma unroll
      for (int pr = 0; pr < 2; ++pr)
        vv[hf][pr] = *(const short8*)&Vc[(hf * 16 + l15) * 64 + (((pr * 4 + lg) ^ (l15 & 7)) * 8)];

#pragma unroll
    for (int mi = 0; mi < 2; ++mi) {
      f32x4 sc[4];
      __builtin_amdgcn_s_setprio(1);
#pragma unroll
      for (int f = 0; f < 4; ++f) {
        f32x4 tq = MFMA_BF16(kf[f][0], qf[mi][0], zf);
        sc[f] = MFMA_BF16(kf[f][1], qf[mi][1], tq);
      }
      __builtin_amdgcn_s_setprio(0);

      float tmax = sc[0][0];
#pragma unroll
      for (int f = 0; f < 4; ++f)
#pragma unroll
        for (int r = 0; r < 4; ++r) tmax = fmaxf(tmax, sc[f][r]);
      tmax = fmaxf(tmax, __shfl_xor(tmax, 16));
      tmax = fmaxf(tmax, __shfl_xor(tmax, 32));

      if (__any(tmax > mrun[mi] + 8.0f)) {  // defer-max (T13)
        float mn = fmaxf(mrun[mi], tmax);
        float scl = __expf(mrun[mi] - mn);
        mrun[mi] = mn;
        lrun[mi] *= scl;
#pragma unroll
        for (int hf = 0; hf < 4; ++hf)
#pragma unroll
          for (int r = 0; r < 4; ++r) acc[mi][hf][r] *= scl;
      }

      float rs = 0.0f;
      short4b pb[4];
#pragma unroll
      for (int f = 0; f < 4; ++f) {
#pragma unroll
        for (int r = 0; r < 4; ++r) {
          float p = __expf(sc[f][r] - mrun[mi]);
          p = (mv[f][r] != 0) ? p : 0.0f;
          rs += p;
          __hip_bfloat16 hb = __float2bfloat16(p);
          pb[f][r] = (short)__builtin_bit_cast(unsigned short, hb);
        }
      }
      rs += __shfl_xor(rs, 16);
      rs += __shfl_xor(rs, 32);
      lrun[mi] += rs;

      __builtin_amdgcn_s_setprio(1);
#pragma unroll
      for (int hf = 0; hf < 4; ++hf)
#pragma unroll
        for (int pr = 0; pr < 2; ++pr) {
          short4b vlo = __builtin_shufflevector(vv[hf][pr], vv[hf][pr], 0, 1, 2, 3);
          short4b vhi = __builtin_shufflevector(vv[hf][pr], vv[hf][pr], 4, 5, 6, 7);
          acc[mi][hf] = MFMA16(vlo, pb[2 * pr], acc[mi][hf]);
          acc[mi][hf] = MFMA16(vhi, pb[2 * pr + 1], acc[mi][hf]);
        }
      __builtin_amdgcn_s_setprio(0);
    }

    __syncthreads();  // drains vmcnt (staged tile ready) + protects buf reuse
  }

#pragma unroll
  for (int mi = 0; mi < 2; ++mi) {
    float inv = 1.0f / lrun[mi];
    const int q = q0 + mi * 16 + l15;
    unsigned short* dst = vals + ((size_t)b * 2048 + q) * 1024 + h * 64 + lg * 4;
#pragma unroll
    for (int hf = 0; hf < 4; ++hf) {
      ushort4 o;
      o.x = f2bf(acc[mi][hf][0] * inv);
      o.y = f2bf(acc[mi][hf][1] * inv);
      o.z = f2bf(acc[mi][hf][2] * inv);
      o.w = f2bf(acc[mi][hf][3] * inv);
      *(ushort4*)(dst + hf * 16) = o;
    }
  }
}

// ---------------------------------------------------------------- GEMM2: output projection
__global__ __launch_bounds__(256, 2) void gemm_out_k(
    const unsigned short* __restrict__ A, const unsigned short* __restrict__ Bw,
    const float* __restrict__ bo, float* __restrict__ out) {
  const int K = 1024;
  __shared__ __align__(16) unsigned short lA[128 * 32];
  __shared__ __align__(16) unsigned short lB[128 * 32];
  const int tid = threadIdx.x;
  const int lane = tid & 63;
  const int w = tid >> 6;
  const int wm = w >> 1, wn = w & 1;
  const int m0 = blockIdx.x * 128, n0 = blockIdx.y * 128;
  const int l15 = lane & 15, lg = lane >> 4;

  const f32x4 zf = {0.0f, 0.0f, 0.0f, 0.0f};
  f32x4 acc[4][4];
#pragma unroll
  for (int mi = 0; mi < 4; ++mi)
#pragma unroll
    for (int ni = 0; ni < 4; ++ni) acc[mi][ni] = zf;

  const int c0 = tid, c1 = tid + 256;
  const int r0 = c0 >> 2, k0c = (c0 & 3) * 8;
  const int r1 = c1 >> 2, k1c = (c1 & 3) * 8;
  const unsigned short* ga0 = A + (size_t)(m0 + r0) * K + k0c;
  const unsigned short* ga1 = A + (size_t)(m0 + r1) * K + k1c;
  const unsigned short* gb0 = Bw + (size_t)(n0 + r0) * K + k0c;
  const unsigned short* gb1 = Bw + (size_t)(n0 + r1) * K + k1c;

  for (int kt = 0; kt < K; kt += 32) {
    __syncthreads();
    gll16(ga0 + kt, lA + c0 * 8);
    gll16(ga1 + kt, lA + c1 * 8);
    gll16(gb0 + kt, lB + c0 * 8);
    gll16(gb1 + kt, lB + c1 * 8);
    __syncthreads();
    short8 af[4], bf[4];
#pragma unroll
    for (int mi = 0; mi < 4; ++mi)
      af[mi] = *(const short8*)&lA[(wm * 64 + mi * 16 + l15) * 32 + lg * 8];
#pragma unroll
    for (int ni = 0; ni < 4; ++ni)
      bf[ni] = *(const short8*)&lB[(wn * 64 + ni * 16 + l15) * 32 + lg * 8];
#pragma unroll
    for (int mi = 0; mi < 4; ++mi)
#pragma unroll
      for (int ni = 0; ni < 4; ++ni)
        acc[mi][ni] = MFMA_BF16(af[mi], bf[ni], acc[mi][ni]);
  }

#pragma unroll
  for (int ni = 0; ni < 4; ++ni) {
    const int n = n0 + wn * 64 + ni * 16 + l15;
    const float bia = bo[n];
#pragma unroll
    for (int mi = 0; mi < 4; ++mi) {
      const int mb = m0 + wm * 64 + mi * 16 + lg * 4;
#pragma unroll
      for (int r = 0; r < 4; ++r)
        out[(size_t)(mb + r) * 1024 + n] = acc[mi][ni][r] + bia;
    }
  }
}

// ---------------------------------------------------------------- launch
extern "C" void kernel_launch(void* const* d_in, const int* in_sizes, int n_in,
                              void* d_out, int out_size, void* d_ws, size_t ws_size,
                              hipStream_t stream) {
  const float* x  = (const float*)d_in[0];
  const int* mask = (const int*)d_in[1];
  const float* Wq = (const float*)d_in[2];
  const float* bq = (const float*)d_in[3];
  const float* Wk = (const float*)d_in[4];
  const float* bk = (const float*)d_in[5];
  const float* Wv = (const float*)d_in[6];
  const float* bv = (const float*)d_in[7];
  const float* Wo = (const float*)d_in[8];
  const float* bo = (const float*)d_in[9];
  float* out = (float*)d_out;

  unsigned short* xb   = (unsigned short*)d_ws;            // 8192*1024
  unsigned short* wqkv = xb + (size_t)8192 * 1024;         // 3072*1024
  unsigned short* wob  = wqkv + (size_t)3072 * 1024;       // 1024*1024
  unsigned short* qb   = wob + (size_t)1024 * 1024;        // 64*2048*64
  unsigned short* kb   = qb + (size_t)64 * 2048 * 64;
  unsigned short* vtb  = kb + (size_t)64 * 2048 * 64;      // tiled V^T
  unsigned short* vals = vtb + (size_t)64 * 2048 * 64;     // 8192*1024

  convert_k<<<dim3(12288), dim3(256), 0, stream>>>(x, Wq, Wk, Wv, Wo, xb, wqkv, wob);
  gemm_qkv_k<<<dim3(64, 24), dim3(256), 0, stream>>>(xb, wqkv, bq, bk, bv, qb, kb, vtb);
  attn_k<<<dim3(1024), dim3(256), 0, stream>>>(qb, kb, vtb, mask, vals);
  gemm_out_k<<<dim3(64, 8), dim3(256), 0, stream>>>(vals, wob, bo, out);
}